// Round 1
// baseline (516.592 us; speedup 1.0000x reference)
//
#include <hip/hip_runtime.h>

#define NN 100000
#define NE 1600000

// ============================================================
// GEMM core: C[M,128] = A[M,128] @ B[128,128]
// block = 256 threads, M-tile = 64 rows, full N=128, K split in 2 passes.
// LDS: xs = A-tile transposed+swizzled [128k][64r] (32KB)
//      ws = B half-tile [64k][128c]               (32KB)   total = 64KB
// thread (rg = tid>>4 rows rg*4..+3, tx = tid&15 cols tx*8..+7): acc[4][8]
// ============================================================

__global__ __launch_bounds__(256) void k_gemm_att(
    const float* __restrict__ A, const float* __restrict__ B,
    const float* __restrict__ att_s, const float* __restrict__ att_d,
    float* __restrict__ H, float* __restrict__ as_out, float* __restrict__ ad_out,
    int M)
{
    __shared__ __align__(16) float xs[128 * 64];
    __shared__ __align__(16) float ws[64 * 128];
    int t = threadIdx.x;
    int row0 = blockIdx.x * 64;

    // stage A tile, transposed with XOR swizzle on 4-float groups
    {
        int r = t >> 2;
        int k0 = (t & 3) * 32;
        const float* ap = A + (size_t)(row0 + r) * 128 + k0;
        bool valid = (row0 + r) < M;
#pragma unroll
        for (int j = 0; j < 8; ++j) {
            float4 v = valid ? *(const float4*)(ap + j * 4) : make_float4(0.f, 0.f, 0.f, 0.f);
            int kb = k0 + j * 4;
            float vv[4] = {v.x, v.y, v.z, v.w};
#pragma unroll
            for (int m = 0; m < 4; ++m) {
                int kk = kb + m;
                int sw = (((r >> 2) ^ (kk & 15)) << 2) | (r & 3);
                xs[kk * 64 + sw] = vv[m];
            }
        }
    }

    int rg = t >> 4;
    int tx = t & 15;
    float acc[4][8];
#pragma unroll
    for (int i = 0; i < 4; ++i)
#pragma unroll
        for (int j = 0; j < 8; ++j) acc[i][j] = 0.f;

    for (int pass = 0; pass < 2; ++pass) {
        __syncthreads();  // xs ready (pass 0) / ws free (pass 1)
        // stage B rows [pass*64, pass*64+64)
#pragma unroll
        for (int j = 0; j < 8; ++j) {
            int fi = j * 256 + t;          // float4 index 0..2047
            int k = fi >> 5;
            int c4 = (fi & 31) * 4;
            *(float4*)(ws + k * 128 + c4) =
                *(const float4*)(B + (size_t)(pass * 64 + k) * 128 + c4);
        }
        __syncthreads();
#pragma unroll 4
        for (int kk = 0; kk < 64; ++kk) {
            int k = pass * 64 + kk;
            float4 a4 = *(const float4*)(xs + k * 64 + ((rg ^ (k & 15)) << 2));
            float4 b0 = *(const float4*)(ws + kk * 128 + tx * 8);
            float4 b1 = *(const float4*)(ws + kk * 128 + tx * 8 + 4);
            float av[4] = {a4.x, a4.y, a4.z, a4.w};
            float bv[8] = {b0.x, b0.y, b0.z, b0.w, b1.x, b1.y, b1.z, b1.w};
#pragma unroll
            for (int i = 0; i < 4; ++i)
#pragma unroll
                for (int j = 0; j < 8; ++j)
                    acc[i][j] = fmaf(av[i], bv[j], acc[i][j]);
        }
    }

    // write H rows
    int c0 = tx * 8;
#pragma unroll
    for (int i = 0; i < 4; ++i) {
        int row = row0 + rg * 4 + i;
        if (row < M) {
            *(float4*)(H + (size_t)row * 128 + c0) =
                make_float4(acc[i][0], acc[i][1], acc[i][2], acc[i][3]);
            *(float4*)(H + (size_t)row * 128 + c0 + 4) =
                make_float4(acc[i][4], acc[i][5], acc[i][6], acc[i][7]);
        }
    }

    // attention logit epilogue: a_src[n][head] = sum_c h*att_src
    int head = tx >> 2;
    int cc = (tx & 3) * 8;
    float asv[8], adv[8];
#pragma unroll
    for (int j = 0; j < 8; ++j) {
        asv[j] = att_s[head * 32 + cc + j];
        adv[j] = att_d[head * 32 + cc + j];
    }
#pragma unroll
    for (int i = 0; i < 4; ++i) {
        float ps = 0.f, pd = 0.f;
#pragma unroll
        for (int j = 0; j < 8; ++j) {
            ps = fmaf(acc[i][j], asv[j], ps);
            pd = fmaf(acc[i][j], adv[j], pd);
        }
        // reduce over the 4 tx-subgroups of this head (lane bits 0-1)
        ps += __shfl_xor(ps, 1); ps += __shfl_xor(ps, 2);
        pd += __shfl_xor(pd, 1); pd += __shfl_xor(pd, 2);
        int row = row0 + rg * 4 + i;
        if ((tx & 3) == 0 && row < M) {
            as_out[row * 4 + head] = ps;
            ad_out[row * 4 + head] = pd;
        }
    }
}

__global__ __launch_bounds__(256) void k_gemm_bias_relu(
    const float* __restrict__ A, const float* __restrict__ B,
    const float* __restrict__ bias, float* __restrict__ Out, int M)
{
    __shared__ __align__(16) float xs[128 * 64];
    __shared__ __align__(16) float ws[64 * 128];
    int t = threadIdx.x;
    int row0 = blockIdx.x * 64;
    {
        int r = t >> 2;
        int k0 = (t & 3) * 32;
        const float* ap = A + (size_t)(row0 + r) * 128 + k0;
        bool valid = (row0 + r) < M;
#pragma unroll
        for (int j = 0; j < 8; ++j) {
            float4 v = valid ? *(const float4*)(ap + j * 4) : make_float4(0.f, 0.f, 0.f, 0.f);
            int kb = k0 + j * 4;
            float vv[4] = {v.x, v.y, v.z, v.w};
#pragma unroll
            for (int m = 0; m < 4; ++m) {
                int kk = kb + m;
                int sw = (((r >> 2) ^ (kk & 15)) << 2) | (r & 3);
                xs[kk * 64 + sw] = vv[m];
            }
        }
    }
    int rg = t >> 4;
    int tx = t & 15;
    float acc[4][8];
#pragma unroll
    for (int i = 0; i < 4; ++i)
#pragma unroll
        for (int j = 0; j < 8; ++j) acc[i][j] = 0.f;

    for (int pass = 0; pass < 2; ++pass) {
        __syncthreads();
#pragma unroll
        for (int j = 0; j < 8; ++j) {
            int fi = j * 256 + t;
            int k = fi >> 5;
            int c4 = (fi & 31) * 4;
            *(float4*)(ws + k * 128 + c4) =
                *(const float4*)(B + (size_t)(pass * 64 + k) * 128 + c4);
        }
        __syncthreads();
#pragma unroll 4
        for (int kk = 0; kk < 64; ++kk) {
            int k = pass * 64 + kk;
            float4 a4 = *(const float4*)(xs + k * 64 + ((rg ^ (k & 15)) << 2));
            float4 b0 = *(const float4*)(ws + kk * 128 + tx * 8);
            float4 b1 = *(const float4*)(ws + kk * 128 + tx * 8 + 4);
            float av[4] = {a4.x, a4.y, a4.z, a4.w};
            float bv[8] = {b0.x, b0.y, b0.z, b0.w, b1.x, b1.y, b1.z, b1.w};
#pragma unroll
            for (int i = 0; i < 4; ++i)
#pragma unroll
                for (int j = 0; j < 8; ++j)
                    acc[i][j] = fmaf(av[i], bv[j], acc[i][j]);
        }
    }
    int c0 = tx * 8;
    float b0v[8];
#pragma unroll
    for (int j = 0; j < 8; ++j) b0v[j] = bias[c0 + j];
#pragma unroll
    for (int i = 0; i < 4; ++i) {
        int row = row0 + rg * 4 + i;
        if (row < M) {
            float o[8];
#pragma unroll
            for (int j = 0; j < 8; ++j) o[j] = fmaxf(acc[i][j] + b0v[j], 0.f);
            *(float4*)(Out + (size_t)row * 128 + c0) = make_float4(o[0], o[1], o[2], o[3]);
            *(float4*)(Out + (size_t)row * 128 + c0 + 4) = make_float4(o[4], o[5], o[6], o[7]);
        }
    }
}

// ============================================================
// CSR build
// ============================================================

__global__ void k_hist(const int* __restrict__ ei, int* __restrict__ deg, int E)
{
    int e = blockIdx.x * 256 + threadIdx.x;
    if (e < E) atomicAdd(&deg[ei[E + e]], 1);
}

__global__ __launch_bounds__(256) void k_scan1(
    const int* __restrict__ deg, int* __restrict__ off, int* __restrict__ bsum, int N)
{
    __shared__ int sd[256];
    int t = threadIdx.x;
    int base = blockIdx.x * 1024 + t * 4;
    int v[4];
#pragma unroll
    for (int m = 0; m < 4; ++m) v[m] = (base + m < N) ? deg[base + m] : 0;
    int tsum = v[0] + v[1] + v[2] + v[3];
    sd[t] = tsum;
    __syncthreads();
    for (int o = 1; o < 256; o <<= 1) {
        int x = (t >= o) ? sd[t - o] : 0;
        __syncthreads();
        sd[t] += x;
        __syncthreads();
    }
    int incl = sd[t];
    int p = incl - tsum;  // exclusive
#pragma unroll
    for (int m = 0; m < 4; ++m) {
        if (base + m < N) off[base + m] = p;
        p += v[m];
    }
    if (t == 255) bsum[blockIdx.x] = incl;
}

__global__ __launch_bounds__(128) void k_scan2(int* __restrict__ bsum, int nb)
{
    __shared__ int sd[128];
    int t = threadIdx.x;
    int v = (t < nb) ? bsum[t] : 0;
    sd[t] = v;
    __syncthreads();
    for (int o = 1; o < 128; o <<= 1) {
        int x = (t >= o) ? sd[t - o] : 0;
        __syncthreads();
        sd[t] += x;
        __syncthreads();
    }
    if (t < nb) bsum[t] = sd[t] - v;  // exclusive
}

__global__ void k_scan3(int* __restrict__ off, const int* __restrict__ bsum, int N)
{
    int i = blockIdx.x * 256 + threadIdx.x;
    if (i < N) off[i] += bsum[i >> 10];
}

__global__ void k_csr(const int* __restrict__ ei, const int* __restrict__ off,
                      int* __restrict__ cur, int* __restrict__ csr, int E)
{
    int e = blockIdx.x * 256 + threadIdx.x;
    if (e < E) {
        int d = ei[E + e];
        int p = off[d] + atomicAdd(&cur[d], 1);
        csr[p] = ei[e];
    }
}

// ============================================================
// Gather/softmax/accumulate: one wave per destination node.
// out[n][c] = (sum_e ex[e][head(c)] * h[src_e][c]) / (sum_e ex[e][head(c)] + 1e-16)
// lane l owns channels l (heads 0-1) and l+64 (heads 2-3).
// ============================================================

__global__ __launch_bounds__(256) void k_gather(
    const float* __restrict__ H, const float* __restrict__ as_,
    const float* __restrict__ ad_, const int* __restrict__ off,
    const int* __restrict__ deg, const int* __restrict__ csr,
    float* __restrict__ outp, int N)
{
    int n = (blockIdx.x << 2) | (threadIdx.x >> 6);
    int lane = threadIdx.x & 63;
    if (n >= N) return;
    int dg = deg[n];
    int base = off[n];
    float4 ad = *(const float4*)(ad_ + (size_t)n * 4);
    float s0 = 0.f, s1 = 0.f, s2 = 0.f, s3 = 0.f;
    float acc0 = 0.f, acc1 = 0.f;
    for (int c0 = 0; c0 < dg; c0 += 64) {
        int idx = c0 + lane;
        int srcv = (idx < dg) ? csr[base + idx] : 0;
        int cnt = min(64, dg - c0);
        for (int j = 0; j < cnt; ++j) {
            int s = __shfl(srcv, j);
            float4 as = *(const float4*)(as_ + (size_t)s * 4);
            float e0 = as.x + ad.x, e1 = as.y + ad.y;
            float e2 = as.z + ad.z, e3 = as.w + ad.w;
            e0 = fmaxf(e0, 0.2f * e0); e1 = fmaxf(e1, 0.2f * e1);
            e2 = fmaxf(e2, 0.2f * e2); e3 = fmaxf(e3, 0.2f * e3);
            float x0 = __expf(e0), x1 = __expf(e1);
            float x2 = __expf(e2), x3 = __expf(e3);
            s0 += x0; s1 += x1; s2 += x2; s3 += x3;
            const float* hp = H + (size_t)s * 128;
            float hv0 = hp[lane];
            float hv1 = hp[64 + lane];
            float w0 = (lane & 32) ? x1 : x0;
            float w1 = (lane & 32) ? x3 : x2;
            acc0 = fmaf(w0, hv0, acc0);
            acc1 = fmaf(w1, hv1, acc1);
        }
    }
    float d0 = (lane & 32) ? s1 : s0;
    float d1 = (lane & 32) ? s3 : s2;
    outp[(size_t)n * 128 + lane] = acc0 / (d0 + 1e-16f);
    outp[(size_t)n * 128 + 64 + lane] = acc1 / (d1 + 1e-16f);
}

// ============================================================

extern "C" void kernel_launch(void* const* d_in, const int* in_sizes, int n_in,
                              void* d_out, int out_size, void* d_ws, size_t ws_size,
                              hipStream_t stream)
{
    const float* x     = (const float*)d_in[0];
    const int*   ei    = (const int*)d_in[1];
    const float* W     = (const float*)d_in[2];
    const float* att_s = (const float*)d_in[3];
    const float* att_d = (const float*)d_in[4];
    const float* lin_w = (const float*)d_in[5];
    const float* lin_b = (const float*)d_in[6];
    float* out = (float*)d_out;
    int N = in_sizes[0] / 128;
    int E = in_sizes[1] / 2;

    char* p = (char*)d_ws;
    auto alloc = [&](size_t bytes) { char* r = p; p += (bytes + 255) & ~(size_t)255; return r; };
    float* H    = (float*)alloc((size_t)N * 128 * 4);
    float* P    = (float*)alloc((size_t)N * 128 * 4);
    float* AS   = (float*)alloc((size_t)N * 4 * 4);
    float* AD   = (float*)alloc((size_t)N * 4 * 4);
    int*   deg  = (int*)alloc((size_t)N * 4);
    int*   cur  = (int*)alloc((size_t)N * 4);
    int*   off  = (int*)alloc((size_t)N * 4);
    int*   bsum = (int*)alloc(4096);
    int*   csr  = (int*)alloc((size_t)E * 4);

    hipMemsetAsync(deg, 0, (size_t)N * 4, stream);
    hipMemsetAsync(cur, 0, (size_t)N * 4, stream);

    int mb = (N + 63) / 64;
    k_gemm_att<<<mb, 256, 0, stream>>>(x, W, att_s, att_d, H, AS, AD, N);
    k_hist<<<(E + 255) / 256, 256, 0, stream>>>(ei, deg, E);
    int nb1 = (N + 1023) / 1024;  // 98 <= 128
    k_scan1<<<nb1, 256, 0, stream>>>(deg, off, bsum, N);
    k_scan2<<<1, 128, 0, stream>>>(bsum, nb1);
    k_scan3<<<(N + 255) / 256, 256, 0, stream>>>(off, bsum, N);
    k_csr<<<(E + 255) / 256, 256, 0, stream>>>(ei, off, cur, csr, E);
    k_gather<<<(N + 3) / 4, 256, 0, stream>>>(H, AS, AD, off, deg, csr, P, N);
    k_gemm_bias_relu<<<mb, 256, 0, stream>>>(P, lin_w, lin_b, out, N);
}

// Round 2
// 469.538 us; speedup vs baseline: 1.1002x; 1.1002x over previous
//
#include <hip/hip_runtime.h>
#include <hip/hip_fp16.h>

#define NN 100000
#define NE 1600000

// ============================================================
// GEMM 1: H = x @ W  (f32 in, fp16 out) + attention-logit epilogue.
// block = 256 threads, M-tile = 64 rows, full N=128, K split in 2 passes.
// LDS: xs = A-tile transposed+swizzled [128k][64r] (32KB)
//      ws = B half-tile [64k][128c]               (32KB)
// thread (rg = tid>>4 rows rg*4..+3, tx = tid&15 cols tx*8..+7): acc[4][8]
// ============================================================

__global__ __launch_bounds__(256) void k_gemm_att(
    const float* __restrict__ A, const float* __restrict__ B,
    const float* __restrict__ att_s, const float* __restrict__ att_d,
    __half* __restrict__ Hh, float* __restrict__ as_out, float* __restrict__ ad_out,
    int M)
{
    __shared__ __align__(16) float xs[128 * 64];
    __shared__ __align__(16) float ws[64 * 128];
    int t = threadIdx.x;
    int row0 = blockIdx.x * 64;

    // stage A tile, transposed with XOR swizzle on 4-float groups
    {
        int r = t >> 2;
        int k0 = (t & 3) * 32;
        const float* ap = A + (size_t)(row0 + r) * 128 + k0;
        bool valid = (row0 + r) < M;
#pragma unroll
        for (int j = 0; j < 8; ++j) {
            float4 v = valid ? *(const float4*)(ap + j * 4) : make_float4(0.f, 0.f, 0.f, 0.f);
            int kb = k0 + j * 4;
            float vv[4] = {v.x, v.y, v.z, v.w};
#pragma unroll
            for (int m = 0; m < 4; ++m) {
                int kk = kb + m;
                int sw = (((r >> 2) ^ (kk & 15)) << 2) | (r & 3);
                xs[kk * 64 + sw] = vv[m];
            }
        }
    }

    int rg = t >> 4;
    int tx = t & 15;
    float acc[4][8];
#pragma unroll
    for (int i = 0; i < 4; ++i)
#pragma unroll
        for (int j = 0; j < 8; ++j) acc[i][j] = 0.f;

    for (int pass = 0; pass < 2; ++pass) {
        __syncthreads();
#pragma unroll
        for (int j = 0; j < 8; ++j) {
            int fi = j * 256 + t;
            int k = fi >> 5;
            int c4 = (fi & 31) * 4;
            *(float4*)(ws + k * 128 + c4) =
                *(const float4*)(B + (size_t)(pass * 64 + k) * 128 + c4);
        }
        __syncthreads();
#pragma unroll 4
        for (int kk = 0; kk < 64; ++kk) {
            int k = pass * 64 + kk;
            float4 a4 = *(const float4*)(xs + k * 64 + ((rg ^ (k & 15)) << 2));
            float4 b0 = *(const float4*)(ws + kk * 128 + tx * 8);
            float4 b1 = *(const float4*)(ws + kk * 128 + tx * 8 + 4);
            float av[4] = {a4.x, a4.y, a4.z, a4.w};
            float bv[8] = {b0.x, b0.y, b0.z, b0.w, b1.x, b1.y, b1.z, b1.w};
#pragma unroll
            for (int i = 0; i < 4; ++i)
#pragma unroll
                for (int j = 0; j < 8; ++j)
                    acc[i][j] = fmaf(av[i], bv[j], acc[i][j]);
        }
    }

    // write H rows in fp16
    int c0 = tx * 8;
#pragma unroll
    for (int i = 0; i < 4; ++i) {
        int row = row0 + rg * 4 + i;
        if (row < M) {
            __half2 ho[4];
#pragma unroll
            for (int k = 0; k < 4; ++k)
                ho[k] = __float22half2_rn(make_float2(acc[i][2 * k], acc[i][2 * k + 1]));
            *(float4*)(Hh + (size_t)row * 128 + c0) = *(float4*)ho;
        }
    }

    // attention logit epilogue: a_src[n][head] = sum_c h*att_src
    int head = tx >> 2;
    int cc = (tx & 3) * 8;
    float asv[8], adv[8];
#pragma unroll
    for (int j = 0; j < 8; ++j) {
        asv[j] = att_s[head * 32 + cc + j];
        adv[j] = att_d[head * 32 + cc + j];
    }
#pragma unroll
    for (int i = 0; i < 4; ++i) {
        float ps = 0.f, pd = 0.f;
#pragma unroll
        for (int j = 0; j < 8; ++j) {
            ps = fmaf(acc[i][j], asv[j], ps);
            pd = fmaf(acc[i][j], adv[j], pd);
        }
        ps += __shfl_xor(ps, 1); ps += __shfl_xor(ps, 2);
        pd += __shfl_xor(pd, 1); pd += __shfl_xor(pd, 2);
        int row = row0 + rg * 4 + i;
        if ((tx & 3) == 0 && row < M) {
            as_out[row * 4 + head] = ps;
            ad_out[row * 4 + head] = pd;
        }
    }
}

// ============================================================
// GEMM 2: Out = relu(P @ lin_w + b)  (fp16 A, f32 B/out)
// ============================================================

__global__ __launch_bounds__(256) void k_gemm_bias_relu(
    const __half* __restrict__ Ah, const float* __restrict__ B,
    const float* __restrict__ bias, float* __restrict__ Out, int M)
{
    __shared__ __align__(16) float xs[128 * 64];
    __shared__ __align__(16) float ws[64 * 128];
    int t = threadIdx.x;
    int row0 = blockIdx.x * 64;
    {
        int r = t >> 2;
        int k0 = (t & 3) * 32;
        const __half* ap = Ah + (size_t)(row0 + r) * 128 + k0;
        bool valid = (row0 + r) < M;
#pragma unroll
        for (int j = 0; j < 4; ++j) {
            float4 raw;
            if (valid) raw = *(const float4*)(ap + j * 8);
            else raw = make_float4(0.f, 0.f, 0.f, 0.f);
            __half2* ph = (__half2*)&raw;
            float f[8];
#pragma unroll
            for (int k = 0; k < 4; ++k) {
                float2 fp = __half22float2(ph[k]);
                f[2 * k] = fp.x; f[2 * k + 1] = fp.y;
            }
            if (!valid) { for (int k = 0; k < 8; ++k) f[k] = 0.f; }
#pragma unroll
            for (int m = 0; m < 8; ++m) {
                int kk = k0 + j * 8 + m;
                int sw = (((r >> 2) ^ (kk & 15)) << 2) | (r & 3);
                xs[kk * 64 + sw] = f[m];
            }
        }
    }
    int rg = t >> 4;
    int tx = t & 15;
    float acc[4][8];
#pragma unroll
    for (int i = 0; i < 4; ++i)
#pragma unroll
        for (int j = 0; j < 8; ++j) acc[i][j] = 0.f;

    for (int pass = 0; pass < 2; ++pass) {
        __syncthreads();
#pragma unroll
        for (int j = 0; j < 8; ++j) {
            int fi = j * 256 + t;
            int k = fi >> 5;
            int c4 = (fi & 31) * 4;
            *(float4*)(ws + k * 128 + c4) =
                *(const float4*)(B + (size_t)(pass * 64 + k) * 128 + c4);
        }
        __syncthreads();
#pragma unroll 4
        for (int kk = 0; kk < 64; ++kk) {
            int k = pass * 64 + kk;
            float4 a4 = *(const float4*)(xs + k * 64 + ((rg ^ (k & 15)) << 2));
            float4 b0 = *(const float4*)(ws + kk * 128 + tx * 8);
            float4 b1 = *(const float4*)(ws + kk * 128 + tx * 8 + 4);
            float av[4] = {a4.x, a4.y, a4.z, a4.w};
            float bv[8] = {b0.x, b0.y, b0.z, b0.w, b1.x, b1.y, b1.z, b1.w};
#pragma unroll
            for (int i = 0; i < 4; ++i)
#pragma unroll
                for (int j = 0; j < 8; ++j)
                    acc[i][j] = fmaf(av[i], bv[j], acc[i][j]);
        }
    }
    int c0 = tx * 8;
    float b0v[8];
#pragma unroll
    for (int j = 0; j < 8; ++j) b0v[j] = bias[c0 + j];
#pragma unroll
    for (int i = 0; i < 4; ++i) {
        int row = row0 + rg * 4 + i;
        if (row < M) {
            float o[8];
#pragma unroll
            for (int j = 0; j < 8; ++j) o[j] = fmaxf(acc[i][j] + b0v[j], 0.f);
            *(float4*)(Out + (size_t)row * 128 + c0) = make_float4(o[0], o[1], o[2], o[3]);
            *(float4*)(Out + (size_t)row * 128 + c0 + 4) = make_float4(o[4], o[5], o[6], o[7]);
        }
    }
}

// ============================================================
// CSR build
// ============================================================

__global__ void k_hist(const int* __restrict__ ei, int* __restrict__ deg, int E)
{
    int e = blockIdx.x * 256 + threadIdx.x;
    if (e < E) atomicAdd(&deg[ei[E + e]], 1);
}

__global__ __launch_bounds__(256) void k_scan1(
    const int* __restrict__ deg, int* __restrict__ off, int* __restrict__ bsum, int N)
{
    __shared__ int sd[256];
    int t = threadIdx.x;
    int base = blockIdx.x * 1024 + t * 4;
    int v[4];
#pragma unroll
    for (int m = 0; m < 4; ++m) v[m] = (base + m < N) ? deg[base + m] : 0;
    int tsum = v[0] + v[1] + v[2] + v[3];
    sd[t] = tsum;
    __syncthreads();
    for (int o = 1; o < 256; o <<= 1) {
        int x = (t >= o) ? sd[t - o] : 0;
        __syncthreads();
        sd[t] += x;
        __syncthreads();
    }
    int incl = sd[t];
    int p = incl - tsum;
#pragma unroll
    for (int m = 0; m < 4; ++m) {
        if (base + m < N) off[base + m] = p;
        p += v[m];
    }
    if (t == 255) bsum[blockIdx.x] = incl;
}

__global__ __launch_bounds__(128) void k_scan2(int* __restrict__ bsum, int nb)
{
    __shared__ int sd[128];
    int t = threadIdx.x;
    int v = (t < nb) ? bsum[t] : 0;
    sd[t] = v;
    __syncthreads();
    for (int o = 1; o < 128; o <<= 1) {
        int x = (t >= o) ? sd[t - o] : 0;
        __syncthreads();
        sd[t] += x;
        __syncthreads();
    }
    if (t < nb) bsum[t] = sd[t] - v;
}

__global__ void k_scan3(int* __restrict__ off, const int* __restrict__ bsum, int N)
{
    int i = blockIdx.x * 256 + threadIdx.x;
    if (i < N) off[i] += bsum[i >> 10];
}

// CSR fill fused with per-edge softmax numerator exp(leaky(a_src+a_dst)).
// Moves the exp work into a fully-parallel per-edge kernel so the gather's
// wave-serial loop doesn't recompute it redundantly on all 64 lanes.
__global__ void k_csr_exw(const int* __restrict__ ei, const int* __restrict__ off,
                          int* __restrict__ cur,
                          const float* __restrict__ as_, const float* __restrict__ ad_,
                          int* __restrict__ csr, float4* __restrict__ exw, int E)
{
    int e = blockIdx.x * 256 + threadIdx.x;
    if (e < E) {
        int s = ei[e];
        int d = ei[E + e];
        int p = off[d] + atomicAdd(&cur[d], 1);
        csr[p] = s;
        float4 as = *(const float4*)(as_ + (size_t)s * 4);
        float4 ad = *(const float4*)(ad_ + (size_t)d * 4);
        float e0 = as.x + ad.x, e1 = as.y + ad.y;
        float e2 = as.z + ad.z, e3 = as.w + ad.w;
        e0 = fmaxf(e0, 0.2f * e0); e1 = fmaxf(e1, 0.2f * e1);
        e2 = fmaxf(e2, 0.2f * e2); e3 = fmaxf(e3, 0.2f * e3);
        exw[p] = make_float4(__expf(e0), __expf(e1), __expf(e2), __expf(e3));
    }
}

// ============================================================
// Gather/accumulate: one wave per destination node.
// Weight phase: coalesced exw loads -> LDS. Main loop: 4 edges/iter,
// 16 lanes x 8 fp16 channels per edge. Normalize at the end.
// ============================================================

__global__ __launch_bounds__(256) void k_gather(
    const __half* __restrict__ Hh, const float4* __restrict__ exw,
    const int* __restrict__ off, const int* __restrict__ deg,
    const int* __restrict__ csr, __half* __restrict__ P, int N)
{
    __shared__ float ex_s[4][256];
    __shared__ int src_s[4][64];
    int wid = threadIdx.x >> 6;
    int lane = threadIdx.x & 63;
    int n = blockIdx.x * 4 + wid;
    if (n >= N) return;
    int dg = deg[n];
    int base = off[n];
    int g = lane >> 4;        // edge sub-slot 0..3
    int li = lane & 15;       // channel group: channels li*8 .. li*8+7
    int hh = li >> 2;         // head of this channel group
    float s0 = 0.f, s1 = 0.f, s2 = 0.f, s3 = 0.f;
    float acc[8] = {0.f, 0.f, 0.f, 0.f, 0.f, 0.f, 0.f, 0.f};

    for (int c0 = 0; c0 < dg; c0 += 64) {
        int cnt = min(64, dg - c0);
        if (lane < cnt) {
            int se = csr[base + c0 + lane];
            float4 xw = exw[base + c0 + lane];
            s0 += xw.x; s1 += xw.y; s2 += xw.z; s3 += xw.w;
            *(float4*)&ex_s[wid][lane * 4] = xw;
            src_s[wid][lane] = se;
        }
        __asm__ volatile("s_waitcnt lgkmcnt(0)" ::: "memory");
        int iters = (cnt + 3) >> 2;
        for (int ii = 0; ii < iters; ++ii) {
            int j = ii * 4 + g;
            bool valid = j < cnt;
            float w = valid ? ex_s[wid][j * 4 + hh] : 0.f;
            int se = valid ? src_s[wid][j] : 0;
            float4 raw = *(const float4*)(Hh + (size_t)se * 128 + li * 8);
            __half2* ph = (__half2*)&raw;
            float2 f0 = __half22float2(ph[0]);
            float2 f1 = __half22float2(ph[1]);
            float2 f2 = __half22float2(ph[2]);
            float2 f3 = __half22float2(ph[3]);
            acc[0] = fmaf(w, f0.x, acc[0]);
            acc[1] = fmaf(w, f0.y, acc[1]);
            acc[2] = fmaf(w, f1.x, acc[2]);
            acc[3] = fmaf(w, f1.y, acc[3]);
            acc[4] = fmaf(w, f2.x, acc[4]);
            acc[5] = fmaf(w, f2.y, acc[5]);
            acc[6] = fmaf(w, f3.x, acc[6]);
            acc[7] = fmaf(w, f3.y, acc[7]);
        }
        __asm__ volatile("s_waitcnt lgkmcnt(0)" ::: "memory");
    }

    // total softmax denominators (each lane holds partials from weight phase)
#pragma unroll
    for (int o = 1; o < 64; o <<= 1) {
        s0 += __shfl_xor(s0, o);
        s1 += __shfl_xor(s1, o);
        s2 += __shfl_xor(s2, o);
        s3 += __shfl_xor(s3, o);
    }
    // combine the 4 edge sub-slots (lanes sharing li)
#pragma unroll
    for (int o = 16; o < 64; o <<= 1)
#pragma unroll
        for (int c = 0; c < 8; ++c) acc[c] += __shfl_xor(acc[c], o);

    float sh = (hh == 0) ? s0 : (hh == 1) ? s1 : (hh == 2) ? s2 : s3;
    float inv = 1.f / (sh + 1e-16f);
    if (g == 0) {
        __half2 o4[4];
#pragma unroll
        for (int k = 0; k < 4; ++k)
            o4[k] = __float22half2_rn(make_float2(acc[2 * k] * inv, acc[2 * k + 1] * inv));
        *(float4*)(P + (size_t)n * 128 + li * 8) = *(float4*)o4;
    }
}

// ============================================================

extern "C" void kernel_launch(void* const* d_in, const int* in_sizes, int n_in,
                              void* d_out, int out_size, void* d_ws, size_t ws_size,
                              hipStream_t stream)
{
    const float* x     = (const float*)d_in[0];
    const int*   ei    = (const int*)d_in[1];
    const float* W     = (const float*)d_in[2];
    const float* att_s = (const float*)d_in[3];
    const float* att_d = (const float*)d_in[4];
    const float* lin_w = (const float*)d_in[5];
    const float* lin_b = (const float*)d_in[6];
    float* out = (float*)d_out;
    int N = in_sizes[0] / 128;
    int E = in_sizes[1] / 2;

    char* p = (char*)d_ws;
    auto alloc = [&](size_t bytes) { char* r = p; p += (bytes + 255) & ~(size_t)255; return r; };
    __half* Hh  = (__half*)alloc((size_t)N * 128 * 2);
    __half* P   = (__half*)alloc((size_t)N * 128 * 2);
    float* AS   = (float*)alloc((size_t)N * 4 * 4);
    float* AD   = (float*)alloc((size_t)N * 4 * 4);
    int*   deg  = (int*)alloc((size_t)N * 4);
    int*   cur  = (int*)alloc((size_t)N * 4);
    int*   off  = (int*)alloc((size_t)N * 4);
    int*   bsum = (int*)alloc(4096);
    int*   csr  = (int*)alloc((size_t)E * 4);
    float4* exw = (float4*)alloc((size_t)E * 16);

    hipMemsetAsync(deg, 0, (size_t)N * 4, stream);
    hipMemsetAsync(cur, 0, (size_t)N * 4, stream);

    int mb = (N + 63) / 64;
    k_gemm_att<<<mb, 256, 0, stream>>>(x, W, att_s, att_d, Hh, AS, AD, N);
    k_hist<<<(E + 255) / 256, 256, 0, stream>>>(ei, deg, E);
    int nb1 = (N + 1023) / 1024;
    k_scan1<<<nb1, 256, 0, stream>>>(deg, off, bsum, N);
    k_scan2<<<1, 128, 0, stream>>>(bsum, nb1);
    k_scan3<<<(N + 255) / 256, 256, 0, stream>>>(off, bsum, N);
    k_csr_exw<<<(E + 255) / 256, 256, 0, stream>>>(ei, off, cur, AS, AD, csr, exw, E);
    k_gather<<<(N + 3) / 4, 256, 0, stream>>>(Hh, exw, off, deg, csr, P, N);
    k_gemm_bias_relu<<<mb, 256, 0, stream>>>(P, lin_w, lin_b, out, N);
}